// Round 4
// baseline (400.688 us; speedup 1.0000x reference)
//
#include <hip/hip_runtime.h>
#include <cstddef>

typedef unsigned short ushort_t;
typedef __attribute__((ext_vector_type(8))) short bf16x8;
typedef __attribute__((ext_vector_type(4))) float f32x4;
typedef __attribute__((ext_vector_type(16))) float f32x16;

// ---------------- workspace layout (float offsets) ----------------
// [0..1048576): p0 (4096x256) -> dots (1024x1024) -> bitmap (524288 words, 2MB)
//               obk (packed ob frags, bf16 6144x128 = 393216 f) at +524288 after argmin
#define WS_P0     0u
#define WS_DOTS   0u
#define WS_BITMAP 0u
#define WS_OBK    524288u
#define WS_HN0    1048576u   /* 4096x256; -> hc (6144x128) at the end */
#define WS_HC     1048576u
#define WS_H1     2097152u   /* 4096x128 */
#define WS_H1N    2621440u   /* 4096x128 */
#define WS_P1     3145728u   /* 4096x128; -> pvb (bf16 packed 128x6144 = 393216 f) */
#define WS_XT     3145728u
#define WS_HN1    3670016u   /* 4096x128; -> sqn (1024) after h2 gemm */
#define WS_SQN    3670016u
#define WS_H2     4194304u   /* 4096x128; -> elist (int2 x 69632) after build_x */
#define WS_ELIST  4194304u
#define WS_X      4718592u   /* 6144x128 */
#define WS_OB     5505024u   /* bf16 6144x128 = 393216 floats */
// ---- contiguous zero region (one memset): ----
#define WS_NEIGH  6291456u   /* 786432 */
#define WS_ROWSUM 7077888u   /* 6144 */
#define WS_SCAL   7084032u   /* 16 floats: [S_all, s1, -, sub]; int ecount at +4 */
#define WS_DEG    7084048u   /* int 4096 */
// ---- end zero region ----
#define WS_NN     7088144u   /* int 1024 */
#define WS_CUR    7089168u   /* int 4096 */
#define WS_ROWPTR 7093264u   /* int 4097 */
#define WS_EIDX   7097361u   /* int 69632 */

__device__ inline ushort_t f2bf(float f) {
  unsigned u = __float_as_uint(f);
  u += 0x7fff + ((u >> 16) & 1);   // round-to-nearest-even
  return (ushort_t)(u >> 16);
}

// async global -> LDS, 16B per lane (dest = wave-uniform base + lane*16)
__device__ inline void gload_lds16(const ushort_t* g, ushort_t* l) {
  __builtin_amdgcn_global_load_lds(
      (const __attribute__((address_space(1))) unsigned int*)g,
      (__attribute__((address_space(3))) unsigned int*)l, 16, 0, 0);
}

// ---------------- generic NT GEMM: C = act(A@B^T (+ A2@B2^T) + bias) -------
__global__ __launch_bounds__(256, 2) void gemm_nt(
    const float* __restrict__ A, int lda,
    const float* __restrict__ B, int ldb,
    const float* __restrict__ A2, int lda2,
    const float* __restrict__ B2, int ldb2,
    const float* __restrict__ bias,
    float* __restrict__ C, int ldc,
    int K, int relu,
    ushort_t* __restrict__ Cb,
    const float* __restrict__ a2scale)
{
  __shared__ float As[16][68];
  __shared__ float Bs[16][68];
  const int tid = threadIdx.x;
  const int tx = tid & 15, ty = tid >> 4;
  const int lr = tid >> 2;
  const int lk = (tid & 3) << 2;
  const int i0 = blockIdx.y << 6;
  const int j0 = blockIdx.x << 6;
  float acc[4][4] = {};
  const int npass = (A2 != nullptr) ? 2 : 1;
  for (int pass = 0; pass < npass; ++pass) {
    const float* Ap = pass ? A2 : A; const int la = pass ? lda2 : lda;
    const float* Bp = pass ? B2 : B; const int lb = pass ? ldb2 : ldb;
    const float sc = (pass && a2scale) ? __frcp_rn(a2scale[i0 + lr] + 1.f) : 1.f;
    for (int k0 = 0; k0 < K; k0 += 16) {
      float4 ag = *(const float4*)(Ap + (size_t)(i0 + lr) * la + (k0 + lk));
      const float4 bg = *(const float4*)(Bp + (size_t)(j0 + lr) * lb + (k0 + lk));
      ag.x *= sc; ag.y *= sc; ag.z *= sc; ag.w *= sc;
      __syncthreads();
      As[lk+0][lr]=ag.x; As[lk+1][lr]=ag.y; As[lk+2][lr]=ag.z; As[lk+3][lr]=ag.w;
      Bs[lk+0][lr]=bg.x; Bs[lk+1][lr]=bg.y; Bs[lk+2][lr]=bg.z; Bs[lk+3][lr]=bg.w;
      __syncthreads();
#pragma unroll
      for (int k = 0; k < 16; ++k) {
        const float4 a4 = *(const float4*)&As[k][ty << 2];
        const float4 b4 = *(const float4*)&Bs[k][tx << 2];
        const float aa[4] = {a4.x, a4.y, a4.z, a4.w};
        const float bb[4] = {b4.x, b4.y, b4.z, b4.w};
#pragma unroll
        for (int ii = 0; ii < 4; ++ii)
#pragma unroll
          for (int jj = 0; jj < 4; ++jj)
            acc[ii][jj] += aa[ii] * bb[jj];
      }
    }
  }
  float badd[4] = {0.f, 0.f, 0.f, 0.f};
  if (bias) {
    const float4 t = *(const float4*)(bias + j0 + (tx << 2));
    badd[0]=t.x; badd[1]=t.y; badd[2]=t.z; badd[3]=t.w;
  }
#pragma unroll
  for (int ii = 0; ii < 4; ++ii) {
    float4 o;
    o.x = acc[ii][0] + badd[0];
    o.y = acc[ii][1] + badd[1];
    o.z = acc[ii][2] + badd[2];
    o.w = acc[ii][3] + badd[3];
    if (relu) { o.x=fmaxf(o.x,0.f); o.y=fmaxf(o.y,0.f); o.z=fmaxf(o.z,0.f); o.w=fmaxf(o.w,0.f); }
    const size_t off = (size_t)(i0 + (ty<<2) + ii) * ldc + j0 + (tx<<2);
    if (Cb) {
      ushort4 ob4;
      ob4.x = f2bf(o.x); ob4.y = f2bf(o.y); ob4.z = f2bf(o.z); ob4.w = f2bf(o.w);
      *(ushort4*)(Cb + off) = ob4;
    } else {
      *(float4*)(C + off) = o;
    }
  }
}

// ---------------- CSR build (bucket edges by dst) ----------------
__global__ void count_k(const int* __restrict__ dst, int* __restrict__ deg, int E) {
  const int e = blockIdx.x * 256 + threadIdx.x;
  if (e < E) atomicAdd(&deg[dst[e]], 1);
}

__global__ __launch_bounds__(1024) void scan_k(const int* __restrict__ deg,
                                               int* __restrict__ rowptr,
                                               int* __restrict__ cursor) {
  __shared__ int sums[1024];
  const int t = threadIdx.x;
  const int4 d = *(const int4*)(deg + (t << 2));
  const int local = d.x + d.y + d.z + d.w;
  sums[t] = local;
  __syncthreads();
  for (int off = 1; off < 1024; off <<= 1) {
    int v = (t >= off) ? sums[t - off] : 0;
    __syncthreads();
    sums[t] += v;
    __syncthreads();
  }
  const int excl = sums[t] - local;
  const int o0 = excl, o1 = o0 + d.x, o2 = o1 + d.y, o3 = o2 + d.z;
  rowptr[(t<<2)+0]=o0; rowptr[(t<<2)+1]=o1; rowptr[(t<<2)+2]=o2; rowptr[(t<<2)+3]=o3;
  cursor[(t<<2)+0]=o0; cursor[(t<<2)+1]=o1; cursor[(t<<2)+2]=o2; cursor[(t<<2)+3]=o3;
  if (t == 1023) rowptr[4096] = sums[1023];
}

__global__ void fill_k(const int* __restrict__ src, const int* __restrict__ dst,
                       int* __restrict__ cursor, int* __restrict__ eidx, int E) {
  const int e = blockIdx.x * 256 + threadIdx.x;
  if (e < E) {
    const int p = atomicAdd(&cursor[dst[e]], 1);
    eidx[p] = src[e];
  }
}

// segment_max as CSR gather. p >= 0 (relu'd) and every segment non-empty
// (self-loops), so init 0 reproduces the isfinite->0 semantics exactly.
__global__ void segmax_k(const float* __restrict__ p, const int* __restrict__ rowptr,
                         const int* __restrict__ eidx, float* __restrict__ hn, int F) {
  const int row = blockIdx.x, f = threadIdx.x;  // blockDim == F
  const int b = rowptr[row], e = rowptr[row + 1];
  float m = 0.f;
  for (int k = b; k < e; ++k) m = fmaxf(m, p[(size_t)eidx[k] * F + f]);
  hn[(size_t)row * F + f] = m;
}

// ---------------- small fused elementwise / reductions ----------------
__device__ inline float wave_sum(float v) {
#pragma unroll
  for (int o = 32; o > 0; o >>= 1) v += __shfl_down(v, o, 64);
  return v;
}

__global__ void relu_l2norm_k(const float* __restrict__ in, float* __restrict__ out) {
  const int row = blockIdx.x, f = threadIdx.x;  // 128 threads
  const float v = fmaxf(in[(size_t)row * 128 + f], 0.f);
  const float ss = wave_sum(v * v);
  __shared__ float w[2];
  if ((f & 63) == 0) w[f >> 6] = ss;
  __syncthreads();
  const float denom = fmaxf(sqrtf(w[0] + w[1]), 1e-12f);
  out[(size_t)row * 128 + f] = v / denom;
}

__global__ void sqn_k(const float* __restrict__ h2, float* __restrict__ sqn) {
  const int row = blockIdx.x, f = threadIdx.x;  // 128 threads
  const float v = h2[(size_t)row * 128 + f];
  const float ss = wave_sum(v * v);
  __shared__ float w[2];
  if ((f & 63) == 0) w[f >> 6] = ss;
  __syncthreads();
  if (f == 0) sqn[row] = w[0] + w[1];
}

// nearest neighbor (excluding self), tie-break smallest index = stable argsort pos 1
__global__ void argmin_k(const float* __restrict__ dots, const float* __restrict__ sqn,
                         int* __restrict__ nn) {
  const int i = blockIdx.x, tid = threadIdx.x;  // 256 threads
  float best = 3.402823466e38f; int bidx = 0x7fffffff;
  const float si = sqn[i];
  for (int j = tid; j < 1024; j += 256) {
    if (j == i) continue;
    float d2 = si + sqn[j] - 2.f * dots[(size_t)i * 1024 + j];
    d2 = fmaxf(d2, 0.f);
    if (d2 < best || (d2 == best && j < bidx)) { best = d2; bidx = j; }
  }
  __shared__ float bv[256]; __shared__ int bi[256];
  bv[tid] = best; bi[tid] = bidx;
  __syncthreads();
  for (int s = 128; s > 0; s >>= 1) {
    if (tid < s) {
      if (bv[tid+s] < bv[tid] || (bv[tid+s] == bv[tid] && bi[tid+s] < bi[tid])) {
        bv[tid] = bv[tid+s]; bi[tid] = bi[tid+s];
      }
    }
    __syncthreads();
  }
  if (tid == 0) nn[i] = bi[0];
}

__global__ void build_x_k(const float* __restrict__ h2, const int* __restrict__ nn,
                          const float* __restrict__ gaps, float* __restrict__ x) {
  const int row = blockIdx.x, f = threadIdx.x;  // 128 threads, grid 6144
  if (row < 4096) {
    x[(size_t)row * 128 + f] = h2[(size_t)row * 128 + f];
  } else {
    const int s = row - 4096, i = s >> 1, r = s & 1;
    const float g = gaps[(i << 1) + r];
    const float c  = h2[(size_t)i * 128 + f];
    const float cn = h2[(size_t)nn[i] * 128 + f];
    x[(size_t)row * 128 + f] = c + g * (cn - c);
  }
}

// ---------------- fragment pre-pack kernels (coalesce the fused loop) -------
// obk[jt*4096 + c*512 + lane*8 + e] = ob[(32jt + (lane&31))*128 + 16c + 8(lane>>5) + e]
// -> every A/Q fragment load in fused_mfma becomes lane-contiguous 16B.
__global__ __launch_bounds__(256) void pack_obk_k(const ushort_t* __restrict__ ob,
                                                  ushort_t* __restrict__ obk) {
  __shared__ ushort_t s[4096];  // [32 rows][128 cols]
  const int jt = blockIdx.x, tid = threadIdx.x;
  const ushort_t* ip = ob + ((size_t)jt << 12);
#pragma unroll
  for (int k = 0; k < 2; ++k)
    *(int4*)(s + (tid << 4) + (k << 3)) = *(const int4*)(ip + (tid << 4) + (k << 3));
  __syncthreads();
  const int u = tid & 31, c = tid >> 5;
  ushort_t* op = obk + ((size_t)jt << 12) + (c << 9);
#pragma unroll
  for (int m = 0; m < 2; ++m) {
    const int l = (u << 1) + m;
    *(int4*)(op + (l << 3)) = *(const int4*)(s + ((l & 31) << 7) + (c << 4) + ((l >> 5) << 3));
  }
}

// pvb[jt*4096 + cc*2048 + ft*512 + lane*8 + e] = f2bf(x[32jt+16cc+8(lane>>5)+e][32ft+(lane&31)])
// -> every PV B fragment load in fused_mfma becomes lane-contiguous 16B.
__global__ __launch_bounds__(256) void pack_pvb_k(const float* __restrict__ x,
                                                  ushort_t* __restrict__ pvb) {
  __shared__ ushort_t s[4096];  // [32 j][128 f] bf16
  const int jt = blockIdx.x, tid = threadIdx.x;
  const float* ip = x + ((size_t)jt << 12);
#pragma unroll
  for (int k = 0; k < 4; ++k) {
    const float4 v = *(const float4*)(ip + (tid << 4) + (k << 2));
    ushort4 h; h.x = f2bf(v.x); h.y = f2bf(v.y); h.z = f2bf(v.z); h.w = f2bf(v.w);
    *(ushort4*)(s + (tid << 4) + (k << 2)) = h;
  }
  __syncthreads();
  const int u = tid & 31, ft = (tid >> 5) & 3, cc = tid >> 7;
  ushort_t* op = pvb + ((size_t)jt << 12) + (cc << 11) + (ft << 9);
#pragma unroll
  for (int m = 0; m < 2; ++m) {
    const int l = (u << 1) + m;
    const int f = (ft << 5) + (l & 31);
    const int jb = (cc << 4) + ((l >> 5) << 3);
    ushort4 o0, o1;
    o0.x = s[(jb + 0) * 128 + f]; o0.y = s[(jb + 1) * 128 + f];
    o0.z = s[(jb + 2) * 128 + f]; o0.w = s[(jb + 3) * 128 + f];
    o1.x = s[(jb + 4) * 128 + f]; o1.y = s[(jb + 5) * 128 + f];
    o1.z = s[(jb + 6) * 128 + f]; o1.w = s[(jb + 7) * 128 + f];
    *(ushort4*)(op + (l << 3) + 0) = o0;
    *(ushort4*)(op + (l << 3) + 4) = o1;
  }
}

// ---------------- edge path: compact distinct cells, then loss ----------------
__global__ void edge_compact_k(const int* __restrict__ src, const int* __restrict__ dst,
                               unsigned* __restrict__ bitmap, int2* __restrict__ elist,
                               int* __restrict__ ecount, int E) {
  const int e = blockIdx.x * 256 + threadIdx.x;
  const int lane = threadIdx.x & 63;
  int d_ = 0, s_ = 0, claimed = 0;
  if (e < E) {
    d_ = dst[e]; s_ = src[e];
    const unsigned cell = ((unsigned)d_ << 12) + (unsigned)s_;
    const unsigned bit = 1u << (cell & 31);
    const unsigned old = atomicOr(&bitmap[cell >> 5], bit);
    claimed = !(old & bit);
  }
  const unsigned long long m = __ballot(claimed);
  int base = 0;
  if (lane == 0 && m) base = atomicAdd(ecount, (int)__popcll(m));
  base = __shfl(base, 0, 64);
  if (claimed) {
    const int pos = base + (int)__popcll(m & ((1ull << lane) - 1ull));
    elist[pos] = make_int2(d_, s_);
  }
}

// one wave per distinct edge (strided): s1 += (sg-1)^2, sub += sg^2
__global__ __launch_bounds__(256) void edge_loss_k(
    const int2* __restrict__ elist, const int* __restrict__ ecount,
    const ushort_t* __restrict__ ob, float* __restrict__ scal) {
  __shared__ float part[2];
  const int tid = threadIdx.x;
  if (tid < 2) part[tid] = 0.f;
  __syncthreads();
  const int lane = tid & 63;
  const int n = *ecount;
  const int nw = gridDim.x << 2;
  float p1 = 0.f, psub = 0.f;
  for (int e = (blockIdx.x << 2) + (tid >> 6); e < n; e += nw) {
    const int2 ed = elist[e];
    const unsigned a = *(const unsigned*)(ob + ((size_t)ed.x << 7) + (lane << 1));
    const unsigned b = *(const unsigned*)(ob + ((size_t)ed.y << 7) + (lane << 1));
    const float a0 = __uint_as_float(a << 16), a1 = __uint_as_float(a & 0xffff0000u);
    const float b0 = __uint_as_float(b << 16), b1 = __uint_as_float(b & 0xffff0000u);
    float v = a0 * b0 + a1 * b1;
    v = wave_sum(v);
    if (lane == 0) {
      const float sg = 1.f / (1.f + __expf(-v));
      p1 += (sg - 1.f) * (sg - 1.f);
      psub += sg * sg;
    }
  }
  if (lane == 0) { atomicAdd(&part[0], p1); atomicAdd(&part[1], psub); }
  __syncthreads();
  if (tid == 0) { atomicAdd(&scal[1], part[0]); atomicAdd(&scal[3], part[1]); }
}

// ---------------- fused MFMA v6: LDS-shared j-tile streams ----------------
// v5 + block-level sharing of the (a, bv) fragment streams: all 4 waves of a
// block consume the SAME j-tiles, so stage each 16KB tile (8KB obk + 8KB pvb)
// once per block into LDS via global_load_lds (packed layout == the linear
// lane-contiguous order gload_lds writes). Double-buffered, 1 barrier/tile.
// Cuts the loop's L2 read traffic 4x (590 MB -> 147 MB).
__global__ __launch_bounds__(256, 2) void fused_mfma(
    const ushort_t* __restrict__ obk,  // packed A/Q frags [192][8][64][8]
    const ushort_t* __restrict__ pvb,  // packed PV B frags [192][2][4][64][8]
    float* __restrict__ neigh,         // 6144x128, pre-zeroed
    float* __restrict__ rowsum,        // 6144, pre-zeroed
    float* __restrict__ scal)          // [S_all, s1, -, sub], pre-zeroed
{
  __shared__ ushort_t stg[2][8192];    // 2 x 16KB: [8 a-frags | 8 bv-frags] x 512 ushorts
  __shared__ float red[256];
  const int tid = threadIdx.x;
  const int w = tid >> 6;
  const int lane = tid & 63;
  const int lo = lane & 31, hi = lane >> 5;
  const int iw = (blockIdx.x << 7) + (w << 5);   // wave's 32-row i-base
  const int it = (blockIdx.x << 2) + w;          // wave's i-tile index
  const int jt0 = blockIdx.y << 4;               // first 32-wide j-tile index
  // loss region i<4096, j<4096 is block-uniform: 4096 = 128 tiles
  const bool sall_ok = (blockIdx.x < 32) && (blockIdx.y < 8);

  // Q-frags (B operand of S^T), persistent: one coalesced 16B/lane load each
  bf16x8 q[8];
  {
    const ushort_t* qp = obk + ((size_t)it << 12) + (lane << 3);
#pragma unroll
    for (int c = 0; c < 8; ++c) q[c] = *(const bf16x8*)(qp + (c << 9));
  }
  f32x16 oacc[4];
#pragma unroll
  for (int ft = 0; ft < 4; ++ft)
#pragma unroll
    for (int r = 0; r < 16; ++r) oacc[ft][r] = 0.f;
  float rs = 0.f, s_all = 0.f;

  // stage: wave w handles chunks [4w..4w+4) of 16x1KB (8 obk + 8 pvb)
#define STAGE(BUF, JT) {                                                     \
    const size_t tb = ((size_t)(JT)) << 12;                                  \
    ushort_t* lb = &stg[BUF][0];                                             \
    _Pragma("unroll")                                                        \
    for (int c_ = 0; c_ < 4; ++c_) {                                         \
      const int ch = (w << 2) + c_;                                          \
      const ushort_t* sp = (ch < 8)                                          \
          ? (obk + tb + ((size_t)ch << 9) + (lane << 3))                     \
          : (pvb + tb + ((size_t)(ch - 8) << 9) + (lane << 3));              \
      gload_lds16(sp, lb + (ch << 9));                                       \
    } }

  STAGE(0, jt0);
  __syncthreads();   // drains vmcnt per-wave, then barrier: tile 0 visible

  for (int t = 0; t < 16; ++t) {
    const int cur = t & 1;
    // issue next tile's stage first (hidden under this tile's compute)
    if (t < 15) STAGE(cur ^ 1, jt0 + t + 1);
    const ushort_t* cb = &stg[cur][0];
    // S^T: two 4-deep accumulator chains; a-frags from LDS (conflict-free)
    bf16x8 a[8];
#pragma unroll
    for (int c = 0; c < 8; ++c) a[c] = *(const bf16x8*)(cb + (c << 9) + (lane << 3));
    f32x16 s0, s1;
#pragma unroll
    for (int r = 0; r < 16; ++r) { s0[r] = 0.f; s1[r] = 0.f; }
#pragma unroll
    for (int c = 0; c < 4; ++c) {
      s0 = __builtin_amdgcn_mfma_f32_32x32x16_bf16(a[c], q[c], s0, 0, 0, 0);
      s1 = __builtin_amdgcn_mfma_f32_32x32x16_bf16(a[c + 4], q[c + 4], s1, 0, 0, 0);
    }
    // PV B-frags from LDS
    bf16x8 bvf[2][4];
#pragma unroll
    for (int cc = 0; cc < 2; ++cc)
#pragma unroll
      for (int ft = 0; ft < 4; ++ft)
        bvf[cc][ft] = *(const bf16x8*)(cb + ((8 + (cc << 2) + ft) << 9) + (lane << 3));
    // sigmoid + threshold + rowsum (per-lane scalar, i = lane&31 fixed)
    float p[16];
    if (sall_ok) {
#pragma unroll
      for (int r = 0; r < 16; ++r) {
        const float v = s0[r] + s1[r];
        const float sg = __builtin_amdgcn_rcpf(1.f + __expf(-v));
        s_all += sg * sg;
        const float tv = (v >= 0.f) ? sg : 0.f;   // sg>=0.5 <=> v>=0
        p[r] = tv; rs += tv;
      }
    } else {
#pragma unroll
      for (int r = 0; r < 16; ++r) {
        const float v = s0[r] + s1[r];
        const float sg = __builtin_amdgcn_rcpf(1.f + __expf(-v));
        const float tv = (v >= 0.f) ? sg : 0.f;
        p[r] = tv; rs += tv;
      }
    }
    // pack P -> bf16 PV A-frags: cvt_pk pairs + permlane32_swap (T12).
    // lane(lo,hi) holds P[j=(r&3)+8(r>>2)+4hi]; swap assembles A[row=i][k=j]:
    //   w0 = swap(pk(p0,p1), pk(p4,p5)) -> (word0, word2); w1 likewise -> (1,3).
#pragma unroll
    for (int cc = 0; cc < 2; ++cc) {
      const int b8 = cc << 3;
      unsigned c01, c23, c45, c67;
      asm("v_cvt_pk_bf16_f32 %0, %1, %2" : "=v"(c01) : "v"(p[b8+0]), "v"(p[b8+1]));
      asm("v_cvt_pk_bf16_f32 %0, %1, %2" : "=v"(c23) : "v"(p[b8+2]), "v"(p[b8+3]));
      asm("v_cvt_pk_bf16_f32 %0, %1, %2" : "=v"(c45) : "v"(p[b8+4]), "v"(p[b8+5]));
      asm("v_cvt_pk_bf16_f32 %0, %1, %2" : "=v"(c67) : "v"(p[b8+6]), "v"(p[b8+7]));
      const auto w0 = __builtin_amdgcn_permlane32_swap((int)c01, (int)c45, false, false);
      const auto w1 = __builtin_amdgcn_permlane32_swap((int)c23, (int)c67, false, false);
      union { int i[4]; bf16x8 h; } u;
      u.i[0] = w0[0]; u.i[1] = w1[0]; u.i[2] = w0[1]; u.i[3] = w1[1];
#pragma unroll
      for (int ft = 0; ft < 4; ++ft)
        oacc[ft] = __builtin_amdgcn_mfma_f32_32x32x16_bf16(u.h, bvf[cc][ft], oacc[ft], 0, 0, 0);
    }
    // all waves done reading stg[cur]; next tile's stage complete & visible
    __syncthreads();
  }
#undef STAGE
  // ---- neigh flush: D row = i-local = (r&3)+8*(r>>2)+4*hi, col f = 32ft+lo ----
#pragma unroll
  for (int ft = 0; ft < 4; ++ft)
#pragma unroll
    for (int r = 0; r < 16; ++r) {
      const int ir = (r & 3) + ((r >> 2) << 3) + (hi << 2);
      atomicAdd(&neigh[(size_t)(iw + ir) * 128 + (ft << 5) + lo], oacc[ft][r]);
    }
  // ---- rowsum: lane pair (hi=0,1) shares i = iw+lo ----
  rs += __shfl_xor(rs, 32, 64);
  if (hi == 0) atomicAdd(&rowsum[iw + lo], rs);
  // ---- S_all block reduction ----
  if (sall_ok) {
    red[tid] = s_all;
    __syncthreads();
    for (int s = 128; s > 0; s >>= 1) { if (tid < s) red[tid] += red[tid + s]; __syncthreads(); }
    if (tid == 0) atomicAdd(&scal[0], red[0]);
  }
}

// logits + y + final loss in one launch
__global__ void logits_y_loss_k(const float* __restrict__ hc, const float* __restrict__ Wclf,
                                const float* __restrict__ bclf, const int* __restrict__ labels,
                                const float* __restrict__ scal, const int* __restrict__ ecount,
                                float* __restrict__ outp) {
  const int i = blockIdx.x, f = threadIdx.x;  // 128 threads
  const float h = hc[(size_t)i * 128 + f];
  const float v0 = wave_sum(h * Wclf[f]);
  const float v1 = wave_sum(h * Wclf[128 + f]);
  __shared__ float w0[2], w1[2];
  if ((f & 63) == 0) { w0[f >> 6] = v0; w1[f >> 6] = v1; }
  __syncthreads();
  if (f == 0) {
    outp[(size_t)i * 2 + 0] = w0[0] + w0[1] + bclf[0];
    outp[(size_t)i * 2 + 1] = w1[0] + w1[1] + bclf[1];
    outp[12288 + i] = (i < 4096) ? (float)labels[i] : 1.f;
    if (i == 0) {
      const float cnt = (float)(*ecount);
      const float neg_w = cnt / (16777216.f - cnt);
      outp[18432] = neg_w * (scal[0] - scal[3]) + scal[1];
    }
  }
}

// ---------------- launcher ----------------
extern "C" void kernel_launch(void* const* d_in, const int* in_sizes, int n_in,
                              void* d_out, int out_size, void* d_ws, size_t ws_size,
                              hipStream_t stream) {
  const float* feat     = (const float*)d_in[0];
  const int*   src      = (const int*)d_in[2];
  const int*   dst      = (const int*)d_in[3];
  const int*   labels   = (const int*)d_in[4];
  const float* W_pool0  = (const float*)d_in[5];
  const float* b_pool0  = (const float*)d_in[6];
  const float* W_self0  = (const float*)d_in[7];
  const float* W_neigh0 = (const float*)d_in[8];
  const float* b0       = (const float*)d_in[9];
  const float* W_pool1  = (const float*)d_in[10];
  const float* b_pool1  = (const float*)d_in[11];
  const float* W_self1  = (const float*)d_in[12];
  const float* W_neigh1 = (const float*)d_in[13];
  const float* b1       = (const float*)d_in[14];
  const float* de_w     = (const float*)d_in[15];
  const float* W_conv   = (const float*)d_in[16];
  const float* W_clf    = (const float*)d_in[17];
  const float* b_clf    = (const float*)d_in[18];
  const float* gaps     = (const float*)d_in[19];
  const int E = in_sizes[2];  // 69632 (E + self-loops)

  float* ws = (float*)d_ws;
  float* p0       = ws + WS_P0;
  float* dots     = ws + WS_DOTS;
  unsigned* bitmap= (unsigned*)(ws + WS_BITMAP);
  ushort_t* obk   = (ushort_t*)(ws + WS_OBK);
  float* hn0      = ws + WS_HN0;
  float* hc       = ws + WS_HC;
  float* h1       = ws + WS_H1;
  float* h1n      = ws + WS_H1N;
  float* p1       = ws + WS_P1;
  ushort_t* pvb   = (ushort_t*)(ws + WS_XT);
  float* hn1      = ws + WS_HN1;
  float* sqn      = ws + WS_SQN;
  float* h2       = ws + WS_H2;
  int2* elist     = (int2*)(ws + WS_ELIST);
  float* x        = ws + WS_X;
  ushort_t* ob    = (ushort_t*)(ws + WS_OB);
  float* neigh    = ws + WS_NEIGH;
  float* rowsum   = ws + WS_ROWSUM;
  float* scal     = ws + WS_SCAL;
  int* ecount     = (int*)(ws + WS_SCAL + 4);
  int* deg        = (int*)(ws + WS_DEG);
  int* nn         = (int*)(ws + WS_NN);
  int* cursor     = (int*)(ws + WS_CUR);
  int* rowptr     = (int*)(ws + WS_ROWPTR);
  int* eidx       = (int*)(ws + WS_EIDX);

  float* outp = (float*)d_out;
  const dim3 blk(256);

  // one contiguous zero region: neigh + rowsum + scal(+ecount) + deg
  hipMemsetAsync(neigh, 0, (size_t)(WS_DEG + 4096 - WS_NEIGH) * 4, stream);

  // CSR bucket-by-dst
  count_k<<<(E + 255) / 256, blk, 0, stream>>>(dst, deg, E);
  scan_k<<<1, 1024, 0, stream>>>(deg, rowptr, cursor);
  fill_k<<<(E + 255) / 256, blk, 0, stream>>>(src, dst, cursor, eidx, E);

  // layer 0
  gemm_nt<<<dim3(4, 64), blk, 0, stream>>>(feat, 256, W_pool0, 256,
                                           nullptr, 0, nullptr, 0,
                                           b_pool0, p0, 256, 256, 1, nullptr, nullptr);
  segmax_k<<<4096, 256, 0, stream>>>(p0, rowptr, eidx, hn0, 256);
  gemm_nt<<<dim3(2, 64), blk, 0, stream>>>(feat, 256, W_self0, 256,
                                           hn0, 256, W_neigh0, 256,
                                           b0, h1, 128, 256, 0, nullptr, nullptr);
  relu_l2norm_k<<<4096, 128, 0, stream>>>(h1, h1n);

  // layer 1
  gemm_nt<<<dim3(2, 64), blk, 0, stream>>>(h1n, 128, W_pool1, 128,
                                           nullptr, 0, nullptr, 0,
                                           b_pool1, p1, 128, 128, 1, nullptr, nullptr);
  segmax_k<<<4096, 128, 0, stream>>>(p1, rowptr, eidx, hn1, 128);
  gemm_nt<<<dim3(2, 64), blk, 0, stream>>>(h1n, 128, W_self1, 128,
                                           hn1, 128, W_neigh1, 128,
                                           b1, h2, 128, 128, 0, nullptr, nullptr);

  // SMOTE
  gemm_nt<<<dim3(16, 16), blk, 0, stream>>>(h2, 128, h2, 128,
                                            nullptr, 0, nullptr, 0,
                                            nullptr, dots, 1024, 128, 0, nullptr, nullptr);
  sqn_k<<<1024, 128, 0, stream>>>(h2, sqn);
  argmin_k<<<1024, 256, 0, stream>>>(dots, sqn, nn);
  // dots dead now -> clear bitmap in its place (obk occupies [524288,917504))
  hipMemsetAsync(bitmap, 0, 524288 * 4, stream);
  build_x_k<<<6144, 128, 0, stream>>>(h2, nn, gaps, x);
  pack_pvb_k<<<192, blk, 0, stream>>>(x, pvb);
  // h2 dead now -> elist lives there; compact distinct adj cells
  edge_compact_k<<<(E + 255) / 256, blk, 0, stream>>>(src, dst, bitmap, elist, ecount, E);

  // decoder gemm writes bf16 directly
  gemm_nt<<<dim3(2, 96), blk, 0, stream>>>(x, 128, de_w, 128,
                                           nullptr, 0, nullptr, 0,
                                           nullptr, nullptr, 128, 128, 0, ob, nullptr);
  pack_obk_k<<<192, blk, 0, stream>>>(ob, obk);
  // sparse loss over distinct edges, then dense fused pass (no adj anywhere)
  edge_loss_k<<<768, blk, 0, stream>>>(elist, ecount, ob, scal);
  fused_mfma<<<dim3(48, 12), blk, 0, stream>>>(obk, pvb, neigh, rowsum, scal);

  // classifier: neigh/(rowsum+1) folded into the gemm's A2 path
  gemm_nt<<<dim3(2, 96), blk, 0, stream>>>(x, 128, W_conv, 256,
                                           neigh, 128, W_conv + 128, 256,
                                           nullptr, hc, 128, 128, 0, nullptr, rowsum);
  logits_y_loss_k<<<6144, 128, 0, stream>>>(hc, W_clf, b_clf, labels, scal, ecount, outp);

  (void)n_in; (void)out_size; (void)ws_size; (void)in_sizes;
}

// Round 5
// 396.179 us; speedup vs baseline: 1.0114x; 1.0114x over previous
//
#include <hip/hip_runtime.h>
#include <cstddef>

typedef unsigned short ushort_t;
typedef __attribute__((ext_vector_type(8))) short bf16x8;
typedef __attribute__((ext_vector_type(4))) float f32x4;
typedef __attribute__((ext_vector_type(16))) float f32x16;

// ---------------- workspace layout (float offsets) ----------------
// [0..1048576): p0 (4096x256) -> dots (1024x1024) -> bitmap (524288 words, 2MB)
//               obk (packed ob frags, bf16 6144x128 = 393216 f) at +524288 after argmin
#define WS_P0     0u
#define WS_DOTS   0u
#define WS_BITMAP 0u
#define WS_OBK    524288u
#define WS_HN0    1048576u   /* 4096x256; -> hc (6144x128) at the end */
#define WS_HC     1048576u
#define WS_H1     2097152u   /* 4096x128 */
#define WS_H1N    2621440u   /* 4096x128 */
#define WS_P1     3145728u   /* 4096x128; -> pvb (bf16 packed 128x6144 = 393216 f) */
#define WS_XT     3145728u
#define WS_HN1    3670016u   /* 4096x128; -> sqn (1024) after h2 gemm */
#define WS_SQN    3670016u
#define WS_H2     4194304u   /* 4096x128; -> elist (int2 x 69632) after build_x */
#define WS_ELIST  4194304u
#define WS_X      4718592u   /* 6144x128 */
#define WS_OB     5505024u   /* bf16 6144x128 = 393216 floats */
#define WS_NEIGH  6291456u   /* 786432 (plain-stored now) */
#define WS_ROWSUM 7077888u   /* 6144  (plain-stored now) */
// ---- contiguous zero region (one memset): ----
#define WS_SCAL   7084032u   /* 16 floats: [S_all, s1, -, sub]; int ecount at +4 */
#define WS_DEG    7084048u   /* int 4096 */
// ---- end zero region ----
#define WS_NN     7088144u   /* int 1024 */
#define WS_CUR    7089168u   /* int 4096 */
#define WS_ROWPTR 7093264u   /* int 4097 */
#define WS_EIDX   7097361u   /* int 69632 */

__device__ inline ushort_t f2bf(float f) {
  unsigned u = __float_as_uint(f);
  u += 0x7fff + ((u >> 16) & 1);   // round-to-nearest-even
  return (ushort_t)(u >> 16);
}

// ---------------- generic NT GEMM: C = act(A@B^T (+ A2@B2^T) + bias) -------
__global__ __launch_bounds__(256, 2) void gemm_nt(
    const float* __restrict__ A, int lda,
    const float* __restrict__ B, int ldb,
    const float* __restrict__ A2, int lda2,
    const float* __restrict__ B2, int ldb2,
    const float* __restrict__ bias,
    float* __restrict__ C, int ldc,
    int K, int relu,
    ushort_t* __restrict__ Cb,
    const float* __restrict__ a2scale)
{
  __shared__ float As[16][68];
  __shared__ float Bs[16][68];
  const int tid = threadIdx.x;
  const int tx = tid & 15, ty = tid >> 4;
  const int lr = tid >> 2;
  const int lk = (tid & 3) << 2;
  const int i0 = blockIdx.y << 6;
  const int j0 = blockIdx.x << 6;
  float acc[4][4] = {};
  const int npass = (A2 != nullptr) ? 2 : 1;
  for (int pass = 0; pass < npass; ++pass) {
    const float* Ap = pass ? A2 : A; const int la = pass ? lda2 : lda;
    const float* Bp = pass ? B2 : B; const int lb = pass ? ldb2 : ldb;
    const float sc = (pass && a2scale) ? __frcp_rn(a2scale[i0 + lr] + 1.f) : 1.f;
    for (int k0 = 0; k0 < K; k0 += 16) {
      float4 ag = *(const float4*)(Ap + (size_t)(i0 + lr) * la + (k0 + lk));
      const float4 bg = *(const float4*)(Bp + (size_t)(j0 + lr) * lb + (k0 + lk));
      ag.x *= sc; ag.y *= sc; ag.z *= sc; ag.w *= sc;
      __syncthreads();
      As[lk+0][lr]=ag.x; As[lk+1][lr]=ag.y; As[lk+2][lr]=ag.z; As[lk+3][lr]=ag.w;
      Bs[lk+0][lr]=bg.x; Bs[lk+1][lr]=bg.y; Bs[lk+2][lr]=bg.z; Bs[lk+3][lr]=bg.w;
      __syncthreads();
#pragma unroll
      for (int k = 0; k < 16; ++k) {
        const float4 a4 = *(const float4*)&As[k][ty << 2];
        const float4 b4 = *(const float4*)&Bs[k][tx << 2];
        const float aa[4] = {a4.x, a4.y, a4.z, a4.w};
        const float bb[4] = {b4.x, b4.y, b4.z, b4.w};
#pragma unroll
        for (int ii = 0; ii < 4; ++ii)
#pragma unroll
          for (int jj = 0; jj < 4; ++jj)
            acc[ii][jj] += aa[ii] * bb[jj];
      }
    }
  }
  float badd[4] = {0.f, 0.f, 0.f, 0.f};
  if (bias) {
    const float4 t = *(const float4*)(bias + j0 + (tx << 2));
    badd[0]=t.x; badd[1]=t.y; badd[2]=t.z; badd[3]=t.w;
  }
#pragma unroll
  for (int ii = 0; ii < 4; ++ii) {
    float4 o;
    o.x = acc[ii][0] + badd[0];
    o.y = acc[ii][1] + badd[1];
    o.z = acc[ii][2] + badd[2];
    o.w = acc[ii][3] + badd[3];
    if (relu) { o.x=fmaxf(o.x,0.f); o.y=fmaxf(o.y,0.f); o.z=fmaxf(o.z,0.f); o.w=fmaxf(o.w,0.f); }
    const size_t off = (size_t)(i0 + (ty<<2) + ii) * ldc + j0 + (tx<<2);
    if (Cb) {
      ushort4 ob4;
      ob4.x = f2bf(o.x); ob4.y = f2bf(o.y); ob4.z = f2bf(o.z); ob4.w = f2bf(o.w);
      *(ushort4*)(Cb + off) = ob4;
    } else {
      *(float4*)(C + off) = o;
    }
  }
}

// ---------------- CSR build (bucket edges by dst) ----------------
__global__ void count_k(const int* __restrict__ dst, int* __restrict__ deg, int E) {
  const int e = blockIdx.x * 256 + threadIdx.x;
  if (e < E) atomicAdd(&deg[dst[e]], 1);
}

__global__ __launch_bounds__(1024) void scan_k(const int* __restrict__ deg,
                                               int* __restrict__ rowptr,
                                               int* __restrict__ cursor) {
  __shared__ int sums[1024];
  const int t = threadIdx.x;
  const int4 d = *(const int4*)(deg + (t << 2));
  const int local = d.x + d.y + d.z + d.w;
  sums[t] = local;
  __syncthreads();
  for (int off = 1; off < 1024; off <<= 1) {
    int v = (t >= off) ? sums[t - off] : 0;
    __syncthreads();
    sums[t] += v;
    __syncthreads();
  }
  const int excl = sums[t] - local;
  const int o0 = excl, o1 = o0 + d.x, o2 = o1 + d.y, o3 = o2 + d.z;
  rowptr[(t<<2)+0]=o0; rowptr[(t<<2)+1]=o1; rowptr[(t<<2)+2]=o2; rowptr[(t<<2)+3]=o3;
  cursor[(t<<2)+0]=o0; cursor[(t<<2)+1]=o1; cursor[(t<<2)+2]=o2; cursor[(t<<2)+3]=o3;
  if (t == 1023) rowptr[4096] = sums[1023];
}

__global__ void fill_k(const int* __restrict__ src, const int* __restrict__ dst,
                       int* __restrict__ cursor, int* __restrict__ eidx, int E) {
  const int e = blockIdx.x * 256 + threadIdx.x;
  if (e < E) {
    const int p = atomicAdd(&cursor[dst[e]], 1);
    eidx[p] = src[e];
  }
}

// segment_max as CSR gather. p >= 0 (relu'd) and every segment non-empty
// (self-loops), so init 0 reproduces the isfinite->0 semantics exactly.
__global__ void segmax_k(const float* __restrict__ p, const int* __restrict__ rowptr,
                         const int* __restrict__ eidx, float* __restrict__ hn, int F) {
  const int row = blockIdx.x, f = threadIdx.x;  // blockDim == F
  const int b = rowptr[row], e = rowptr[row + 1];
  float m = 0.f;
  for (int k = b; k < e; ++k) m = fmaxf(m, p[(size_t)eidx[k] * F + f]);
  hn[(size_t)row * F + f] = m;
}

// ---------------- small fused elementwise / reductions ----------------
__device__ inline float wave_sum(float v) {
#pragma unroll
  for (int o = 32; o > 0; o >>= 1) v += __shfl_down(v, o, 64);
  return v;
}

__global__ void relu_l2norm_k(const float* __restrict__ in, float* __restrict__ out) {
  const int row = blockIdx.x, f = threadIdx.x;  // 128 threads
  const float v = fmaxf(in[(size_t)row * 128 + f], 0.f);
  const float ss = wave_sum(v * v);
  __shared__ float w[2];
  if ((f & 63) == 0) w[f >> 6] = ss;
  __syncthreads();
  const float denom = fmaxf(sqrtf(w[0] + w[1]), 1e-12f);
  out[(size_t)row * 128 + f] = v / denom;
}

__global__ void sqn_k(const float* __restrict__ h2, float* __restrict__ sqn) {
  const int row = blockIdx.x, f = threadIdx.x;  // 128 threads
  const float v = h2[(size_t)row * 128 + f];
  const float ss = wave_sum(v * v);
  __shared__ float w[2];
  if ((f & 63) == 0) w[f >> 6] = ss;
  __syncthreads();
  if (f == 0) sqn[row] = w[0] + w[1];
}

// nearest neighbor (excluding self), tie-break smallest index = stable argsort pos 1
__global__ void argmin_k(const float* __restrict__ dots, const float* __restrict__ sqn,
                         int* __restrict__ nn) {
  const int i = blockIdx.x, tid = threadIdx.x;  // 256 threads
  float best = 3.402823466e38f; int bidx = 0x7fffffff;
  const float si = sqn[i];
  for (int j = tid; j < 1024; j += 256) {
    if (j == i) continue;
    float d2 = si + sqn[j] - 2.f * dots[(size_t)i * 1024 + j];
    d2 = fmaxf(d2, 0.f);
    if (d2 < best || (d2 == best && j < bidx)) { best = d2; bidx = j; }
  }
  __shared__ float bv[256]; __shared__ int bi[256];
  bv[tid] = best; bi[tid] = bidx;
  __syncthreads();
  for (int s = 128; s > 0; s >>= 1) {
    if (tid < s) {
      if (bv[tid+s] < bv[tid] || (bv[tid+s] == bv[tid] && bi[tid+s] < bi[tid])) {
        bv[tid] = bv[tid+s]; bi[tid] = bi[tid+s];
      }
    }
    __syncthreads();
  }
  if (tid == 0) nn[i] = bi[0];
}

__global__ void build_x_k(const float* __restrict__ h2, const int* __restrict__ nn,
                          const float* __restrict__ gaps, float* __restrict__ x) {
  const int row = blockIdx.x, f = threadIdx.x;  // 128 threads, grid 6144
  if (row < 4096) {
    x[(size_t)row * 128 + f] = h2[(size_t)row * 128 + f];
  } else {
    const int s = row - 4096, i = s >> 1, r = s & 1;
    const float g = gaps[(i << 1) + r];
    const float c  = h2[(size_t)i * 128 + f];
    const float cn = h2[(size_t)nn[i] * 128 + f];
    x[(size_t)row * 128 + f] = c + g * (cn - c);
  }
}

// ---------------- fragment pre-pack kernels (coalesce the fused loop) -------
// obk[jt*4096 + c*512 + lane*8 + e] = ob[(32jt + (lane&31))*128 + 16c + 8(lane>>5) + e]
// -> every A/Q fragment load in fused_mfma becomes lane-contiguous 16B.
__global__ __launch_bounds__(256) void pack_obk_k(const ushort_t* __restrict__ ob,
                                                  ushort_t* __restrict__ obk) {
  __shared__ ushort_t s[4096];  // [32 rows][128 cols]
  const int jt = blockIdx.x, tid = threadIdx.x;
  const ushort_t* ip = ob + ((size_t)jt << 12);
#pragma unroll
  for (int k = 0; k < 2; ++k)
    *(int4*)(s + (tid << 4) + (k << 3)) = *(const int4*)(ip + (tid << 4) + (k << 3));
  __syncthreads();
  const int u = tid & 31, c = tid >> 5;
  ushort_t* op = obk + ((size_t)jt << 12) + (c << 9);
#pragma unroll
  for (int m = 0; m < 2; ++m) {
    const int l = (u << 1) + m;
    *(int4*)(op + (l << 3)) = *(const int4*)(s + ((l & 31) << 7) + (c << 4) + ((l >> 5) << 3));
  }
}

// pvb[jt*4096 + cc*2048 + ft*512 + lane*8 + e] = f2bf(x[32jt+16cc+8(lane>>5)+e][32ft+(lane&31)])
// -> every PV B fragment load in fused_mfma becomes lane-contiguous 16B.
__global__ __launch_bounds__(256) void pack_pvb_k(const float* __restrict__ x,
                                                  ushort_t* __restrict__ pvb) {
  __shared__ ushort_t s[4096];  // [32 j][128 f] bf16
  const int jt = blockIdx.x, tid = threadIdx.x;
  const float* ip = x + ((size_t)jt << 12);
#pragma unroll
  for (int k = 0; k < 4; ++k) {
    const float4 v = *(const float4*)(ip + (tid << 4) + (k << 2));
    ushort4 h; h.x = f2bf(v.x); h.y = f2bf(v.y); h.z = f2bf(v.z); h.w = f2bf(v.w);
    *(ushort4*)(s + (tid << 4) + (k << 2)) = h;
  }
  __syncthreads();
  const int u = tid & 31, ft = (tid >> 5) & 3, cc = tid >> 7;
  ushort_t* op = pvb + ((size_t)jt << 12) + (cc << 11) + (ft << 9);
#pragma unroll
  for (int m = 0; m < 2; ++m) {
    const int l = (u << 1) + m;
    const int f = (ft << 5) + (l & 31);
    const int jb = (cc << 4) + ((l >> 5) << 3);
    ushort4 o0, o1;
    o0.x = s[(jb + 0) * 128 + f]; o0.y = s[(jb + 1) * 128 + f];
    o0.z = s[(jb + 2) * 128 + f]; o0.w = s[(jb + 3) * 128 + f];
    o1.x = s[(jb + 4) * 128 + f]; o1.y = s[(jb + 5) * 128 + f];
    o1.z = s[(jb + 6) * 128 + f]; o1.w = s[(jb + 7) * 128 + f];
    *(ushort4*)(op + (l << 3) + 0) = o0;
    *(ushort4*)(op + (l << 3) + 4) = o1;
  }
}

// ---------------- edge path: compact distinct cells, then loss ----------------
__global__ void edge_compact_k(const int* __restrict__ src, const int* __restrict__ dst,
                               unsigned* __restrict__ bitmap, int2* __restrict__ elist,
                               int* __restrict__ ecount, int E) {
  const int e = blockIdx.x * 256 + threadIdx.x;
  const int lane = threadIdx.x & 63;
  int d_ = 0, s_ = 0, claimed = 0;
  if (e < E) {
    d_ = dst[e]; s_ = src[e];
    const unsigned cell = ((unsigned)d_ << 12) + (unsigned)s_;
    const unsigned bit = 1u << (cell & 31);
    const unsigned old = atomicOr(&bitmap[cell >> 5], bit);
    claimed = !(old & bit);
  }
  const unsigned long long m = __ballot(claimed);
  int base = 0;
  if (lane == 0 && m) base = atomicAdd(ecount, (int)__popcll(m));
  base = __shfl(base, 0, 64);
  if (claimed) {
    const int pos = base + (int)__popcll(m & ((1ull << lane) - 1ull));
    elist[pos] = make_int2(d_, s_);
  }
}

// one wave per distinct edge (strided): s1 += (sg-1)^2, sub += sg^2
__global__ __launch_bounds__(256) void edge_loss_k(
    const int2* __restrict__ elist, const int* __restrict__ ecount,
    const ushort_t* __restrict__ ob, float* __restrict__ scal) {
  __shared__ float part[2];
  const int tid = threadIdx.x;
  if (tid < 2) part[tid] = 0.f;
  __syncthreads();
  const int lane = tid & 63;
  const int n = *ecount;
  const int nw = gridDim.x << 2;
  float p1 = 0.f, psub = 0.f;
  for (int e = (blockIdx.x << 2) + (tid >> 6); e < n; e += nw) {
    const int2 ed = elist[e];
    const unsigned a = *(const unsigned*)(ob + ((size_t)ed.x << 7) + (lane << 1));
    const unsigned b = *(const unsigned*)(ob + ((size_t)ed.y << 7) + (lane << 1));
    const float a0 = __uint_as_float(a << 16), a1 = __uint_as_float(a & 0xffff0000u);
    const float b0 = __uint_as_float(b << 16), b1 = __uint_as_float(b & 0xffff0000u);
    float v = a0 * b0 + a1 * b1;
    v = wave_sum(v);
    if (lane == 0) {
      const float sg = 1.f / (1.f + __expf(-v));
      p1 += (sg - 1.f) * (sg - 1.f);
      psub += sg * sg;
    }
  }
  if (lane == 0) { atomicAdd(&part[0], p1); atomicAdd(&part[1], psub); }
  __syncthreads();
  if (tid == 0) { atomicAdd(&scal[1], part[0]); atomicAdd(&scal[3], part[1]); }
}

// ---------------- fused MFMA v7: one block per i-tile, zero global atomics --
// Post-mortem r3/r4: loads were never the bottleneck — the 9.4M contended
// device-scope atomicAdds (WRITE_SIZE 37MB == atomic bytes) were. New shape:
// grid (192): block = 4 waves sharing ONE 32-row i-tile, each wave streams 48
// of the 192 j-tiles (stride 4). Partials combined across waves with LDS
// ds_add_f32, then ONE plain coalesced store per neigh element (37MB RMW ->
// 3MB stores). rowsum likewise. Loop = v5's direct packed-L2 streaming.
__global__ __launch_bounds__(256, 2) void fused_mfma(
    const ushort_t* __restrict__ obk,  // packed A/Q frags [192][8][64][8]
    const ushort_t* __restrict__ pvb,  // packed PV B frags [192][2][4][64][8]
    float* __restrict__ neigh,         // 6144x128 (plain-stored)
    float* __restrict__ rowsum,        // 6144 (plain-stored)
    float* __restrict__ scal)          // [S_all, s1, -, sub], pre-zeroed
{
  __shared__ float acc_lds[64][64];    // 16KB, e-major: [ft*16+r][lane]
  __shared__ float rsum_lds[32];
  __shared__ float red[256];
  const int tid = threadIdx.x;
  const int w = tid >> 6;
  const int lane = tid & 63;
  const int lo = lane & 31, hi = lane >> 5;
  const int it = blockIdx.x;           // block's i-tile (32 rows)
  const int iw = it << 5;
  const bool sall_ok = (it < 128);     // loss region i < 4096

  // zero LDS accumulators
  {
    const f32x4 z4 = (f32x4){0.f, 0.f, 0.f, 0.f};
#pragma unroll
    for (int z = 0; z < 4; ++z)
      *(f32x4*)(&acc_lds[0][0] + (tid << 4) + (z << 2)) = z4;
    if (tid < 32) rsum_lds[tid] = 0.f;
  }
  __syncthreads();

  // Q-frags (B operand of S^T), persistent; all 4 waves share the i-tile
  bf16x8 q[8];
  {
    const ushort_t* qp = obk + ((size_t)it << 12) + (lane << 3);
#pragma unroll
    for (int c = 0; c < 8; ++c) q[c] = *(const bf16x8*)(qp + (c << 9));
  }
  f32x16 oacc[4];
#pragma unroll
  for (int ft = 0; ft < 4; ++ft)
#pragma unroll
    for (int r = 0; r < 16; ++r) oacc[ft][r] = 0.f;
  float rs = 0.f, s_all = 0.f;

  // K-frags (A operand) for wave's first tile (jt = w)
  bf16x8 a[8];
  {
    const ushort_t* kp = obk + ((size_t)w << 12) + (lane << 3);
#pragma unroll
    for (int c = 0; c < 8; ++c) a[c] = *(const bf16x8*)(kp + (c << 9));
  }

  for (int k = 0; k < 48; ++k) {
    const int jt = w + (k << 2);       // wave-strided j-tile
    // PV B-frags for THIS tile — issue first (consumed after sigmoid)
    bf16x8 bvf[2][4];
    {
      const ushort_t* vp = pvb + ((size_t)jt << 12) + (lane << 3);
#pragma unroll
      for (int cc = 0; cc < 2; ++cc)
#pragma unroll
        for (int ft = 0; ft < 4; ++ft)
          bvf[cc][ft] = *(const bf16x8*)(vp + (cc << 11) + (ft << 9));
    }
    // S^T: two 4-deep accumulator chains (a already in regs)
    f32x16 s0, s1;
#pragma unroll
    for (int r = 0; r < 16; ++r) { s0[r] = 0.f; s1[r] = 0.f; }
#pragma unroll
    for (int c = 0; c < 4; ++c) {
      s0 = __builtin_amdgcn_mfma_f32_32x32x16_bf16(a[c], q[c], s0, 0, 0, 0);
      s1 = __builtin_amdgcn_mfma_f32_32x32x16_bf16(a[c + 4], q[c + 4], s1, 0, 0, 0);
    }
    // a[] free: prefetch NEXT tile's K-frags (cover = sigmoid + PV)
    if (k < 47) {
      const ushort_t* kp = obk + ((size_t)(jt + 4) << 12) + (lane << 3);
#pragma unroll
      for (int c = 0; c < 8; ++c) a[c] = *(const bf16x8*)(kp + (c << 9));
    }
    // sigmoid + threshold + rowsum (per-lane scalar, i = lane&31 fixed)
    float p[16];
    if (sall_ok && k < 32) {           // jt = w+4k < 128 <=> k < 32
#pragma unroll
      for (int r = 0; r < 16; ++r) {
        const float v = s0[r] + s1[r];
        const float sg = __builtin_amdgcn_rcpf(1.f + __expf(-v));
        s_all += sg * sg;
        const float tv = (v >= 0.f) ? sg : 0.f;   // sg>=0.5 <=> v>=0
        p[r] = tv; rs += tv;
      }
    } else {
#pragma unroll
      for (int r = 0; r < 16; ++r) {
        const float v = s0[r] + s1[r];
        const float sg = __builtin_amdgcn_rcpf(1.f + __expf(-v));
        const float tv = (v >= 0.f) ? sg : 0.f;
        p[r] = tv; rs += tv;
      }
    }
    // pack P -> bf16 PV A-frags: cvt_pk pairs + permlane32_swap (T12).
#pragma unroll
    for (int cc = 0; cc < 2; ++cc) {
      const int b8 = cc << 3;
      unsigned c01, c23, c45, c67;
      asm("v_cvt_pk_bf16_f32 %0, %1, %2" : "=v"(c01) : "v"(p[b8+0]), "v"(p[b8+1]));
      asm("v_cvt_pk_bf16_f32 %0, %1, %2" : "=v"(c23) : "v"(p[b8+2]), "v"(p[b8+3]));
      asm("v_cvt_pk_bf16_f32 %0, %1, %2" : "=v"(c45) : "v"(p[b8+4]), "v"(p[b8+5]));
      asm("v_cvt_pk_bf16_f32 %0, %1, %2" : "=v"(c67) : "v"(p[b8+6]), "v"(p[b8+7]));
      const auto w0 = __builtin_amdgcn_permlane32_swap((int)c01, (int)c45, false, false);
      const auto w1 = __builtin_amdgcn_permlane32_swap((int)c23, (int)c67, false, false);
      union { int i[4]; bf16x8 h; } u;
      u.i[0] = w0[0]; u.i[1] = w1[0]; u.i[2] = w0[1]; u.i[3] = w1[1];
#pragma unroll
      for (int ft = 0; ft < 4; ++ft)
        oacc[ft] = __builtin_amdgcn_mfma_f32_32x32x16_bf16(u.h, bvf[cc][ft], oacc[ft], 0, 0, 0);
    }
  }
  // ---- combine the 4 waves' partials in LDS (ds_add_f32, on-CU) ----
#pragma unroll
  for (int ft = 0; ft < 4; ++ft)
#pragma unroll
    for (int r = 0; r < 16; ++r)
      atomicAdd(&acc_lds[(ft << 4) + r][lane], oacc[ft][r]);
  rs += __shfl_xor(rs, 32, 64);
  if (hi == 0) atomicAdd(&rsum_lds[lo], rs);
  __syncthreads();
  // ---- plain coalesced store: 32 rows x 128 cols of neigh ----
  // element (e=ft*16+r, lane=hi*32+lo) <-> row g=(r&3)+8(r>>2)+4hi, col ft*32+lo
#pragma unroll
  for (int z = 0; z < 4; ++z) {
    const int idx = (z << 8) + tid;    // 0..1023 float4-slots
    const int g = idx >> 5;            // row 0..31
    const int cq = idx & 31;           // float4-col 0..31
    const int ft = cq >> 3;
    const int lo4 = (cq & 7) << 2;
    const int hig = (g >> 2) & 1;
    const int r = (g & 3) + ((g >> 3) << 2);
    *(float4*)(neigh + (size_t)(iw + g) * 128 + (cq << 2)) =
        *(const float4*)&acc_lds[(ft << 4) + r][(hig << 5) + lo4];
  }
  if (tid < 32) rowsum[iw + tid] = rsum_lds[tid];
  // ---- S_all block reduction (block-uniform branch) ----
  if (sall_ok) {
    red[tid] = s_all;
    __syncthreads();
    for (int s = 128; s > 0; s >>= 1) { if (tid < s) red[tid] += red[tid + s]; __syncthreads(); }
    if (tid == 0) atomicAdd(&scal[0], red[0]);
  }
}

// logits + y + final loss in one launch
__global__ void logits_y_loss_k(const float* __restrict__ hc, const float* __restrict__ Wclf,
                                const float* __restrict__ bclf, const int* __restrict__ labels,
                                const float* __restrict__ scal, const int* __restrict__ ecount,
                                float* __restrict__ outp) {
  const int i = blockIdx.x, f = threadIdx.x;  // 128 threads
  const float h = hc[(size_t)i * 128 + f];
  const float v0 = wave_sum(h * Wclf[f]);
  const float v1 = wave_sum(h * Wclf[128 + f]);
  __shared__ float w0[2], w1[2];
  if ((f & 63) == 0) { w0[f >> 6] = v0; w1[f >> 6] = v1; }
  __syncthreads();
  if (f == 0) {
    outp[(size_t)i * 2 + 0] = w0[0] + w0[1] + bclf[0];
    outp[(size_t)i * 2 + 1] = w1[0] + w1[1] + bclf[1];
    outp[12288 + i] = (i < 4096) ? (float)labels[i] : 1.f;
    if (i == 0) {
      const float cnt = (float)(*ecount);
      const float neg_w = cnt / (16777216.f - cnt);
      outp[18432] = neg_w * (scal[0] - scal[3]) + scal[1];
    }
  }
}

// ---------------- launcher ----------------
extern "C" void kernel_launch(void* const* d_in, const int* in_sizes, int n_in,
                              void* d_out, int out_size, void* d_ws, size_t ws_size,
                              hipStream_t stream) {
  const float* feat     = (const float*)d_in[0];
  const int*   src      = (const int*)d_in[2];
  const int*   dst      = (const int*)d_in[3];
  const int*   labels   = (const int*)d_in[4];
  const float* W_pool0  = (const float*)d_in[5];
  const float* b_pool0  = (const float*)d_in[6];
  const float* W_self0  = (const float*)d_in[7];
  const float* W_neigh0 = (const float*)d_in[8];
  const float* b0       = (const float*)d_in[9];
  const float* W_pool1  = (const float*)d_in[10];
  const float* b_pool1  = (const float*)d_in[11];
  const float* W_self1  = (const float*)d_in[12];
  const float* W_neigh1 = (const float*)d_in[13];
  const float* b1       = (const float*)d_in[14];
  const float* de_w     = (const float*)d_in[15];
  const float* W_conv   = (const float*)d_in[16];
  const float* W_clf    = (const float*)d_in[17];
  const float* b_clf    = (const float*)d_in[18];
  const float* gaps     = (const float*)d_in[19];
  const int E = in_sizes[2];  // 69632 (E + self-loops)

  float* ws = (float*)d_ws;
  float* p0       = ws + WS_P0;
  float* dots     = ws + WS_DOTS;
  unsigned* bitmap= (unsigned*)(ws + WS_BITMAP);
  ushort_t* obk   = (ushort_t*)(ws + WS_OBK);
  float* hn0      = ws + WS_HN0;
  float* hc       = ws + WS_HC;
  float* h1       = ws + WS_H1;
  float* h1n      = ws + WS_H1N;
  float* p1       = ws + WS_P1;
  ushort_t* pvb   = (ushort_t*)(ws + WS_XT);
  float* hn1      = ws + WS_HN1;
  float* sqn      = ws + WS_SQN;
  float* h2       = ws + WS_H2;
  int2* elist     = (int2*)(ws + WS_ELIST);
  float* x        = ws + WS_X;
  ushort_t* ob    = (ushort_t*)(ws + WS_OB);
  float* neigh    = ws + WS_NEIGH;
  float* rowsum   = ws + WS_ROWSUM;
  float* scal     = ws + WS_SCAL;
  int* ecount     = (int*)(ws + WS_SCAL + 4);
  int* deg        = (int*)(ws + WS_DEG);
  int* nn         = (int*)(ws + WS_NN);
  int* cursor     = (int*)(ws + WS_CUR);
  int* rowptr     = (int*)(ws + WS_ROWPTR);
  int* eidx       = (int*)(ws + WS_EIDX);

  float* outp = (float*)d_out;
  const dim3 blk(256);

  // zero region: scal(+ecount) + deg only (neigh/rowsum are plain-stored now)
  hipMemsetAsync(scal, 0, (size_t)(WS_DEG + 4096 - WS_SCAL) * 4, stream);

  // CSR bucket-by-dst
  count_k<<<(E + 255) / 256, blk, 0, stream>>>(dst, deg, E);
  scan_k<<<1, 1024, 0, stream>>>(deg, rowptr, cursor);
  fill_k<<<(E + 255) / 256, blk, 0, stream>>>(src, dst, cursor, eidx, E);

  // layer 0
  gemm_nt<<<dim3(4, 64), blk, 0, stream>>>(feat, 256, W_pool0, 256,
                                           nullptr, 0, nullptr, 0,
                                           b_pool0, p0, 256, 256, 1, nullptr, nullptr);
  segmax_k<<<4096, 256, 0, stream>>>(p0, rowptr, eidx, hn0, 256);
  gemm_nt<<<dim3(2, 64), blk, 0, stream>>>(feat, 256, W_self0, 256,
                                           hn0, 256, W_neigh0, 256,
                                           b0, h1, 128, 256, 0, nullptr, nullptr);
  relu_l2norm_k<<<4096, 128, 0, stream>>>(h1, h1n);

  // layer 1
  gemm_nt<<<dim3(2, 64), blk, 0, stream>>>(h1n, 128, W_pool1, 128,
                                           nullptr, 0, nullptr, 0,
                                           b_pool1, p1, 128, 128, 1, nullptr, nullptr);
  segmax_k<<<4096, 128, 0, stream>>>(p1, rowptr, eidx, hn1, 128);
  gemm_nt<<<dim3(2, 64), blk, 0, stream>>>(h1n, 128, W_self1, 128,
                                           hn1, 128, W_neigh1, 128,
                                           b1, h2, 128, 128, 0, nullptr, nullptr);

  // SMOTE
  gemm_nt<<<dim3(16, 16), blk, 0, stream>>>(h2, 128, h2, 128,
                                            nullptr, 0, nullptr, 0,
                                            nullptr, dots, 1024, 128, 0, nullptr, nullptr);
  sqn_k<<<1024, 128, 0, stream>>>(h2, sqn);
  argmin_k<<<1024, 256, 0, stream>>>(dots, sqn, nn);
  // dots dead now -> clear bitmap in its place (obk occupies [524288,917504))
  hipMemsetAsync(bitmap, 0, 524288 * 4, stream);
  build_x_k<<<6144, 128, 0, stream>>>(h2, nn, gaps, x);
  pack_pvb_k<<<192, blk, 0, stream>>>(x, pvb);
  // h2 dead now -> elist lives there; compact distinct adj cells
  edge_compact_k<<<(E + 255) / 256, blk, 0, stream>>>(src, dst, bitmap, elist, ecount, E);

  // decoder gemm writes bf16 directly
  gemm_nt<<<dim3(2, 96), blk, 0, stream>>>(x, 128, de_w, 128,
                                           nullptr, 0, nullptr, 0,
                                           nullptr, nullptr, 128, 128, 0, ob, nullptr);
  pack_obk_k<<<192, blk, 0, stream>>>(ob, obk);
  // sparse loss over distinct edges, then dense fused pass (no adj anywhere)
  edge_loss_k<<<768, blk, 0, stream>>>(elist, ecount, ob, scal);
  fused_mfma<<<dim3(192), blk, 0, stream>>>(obk, pvb, neigh, rowsum, scal);

  // classifier: neigh/(rowsum+1) folded into the gemm's A2 path
  gemm_nt<<<dim3(2, 96), blk, 0, stream>>>(x, 128, W_conv, 256,
                                           neigh, 128, W_conv + 128, 256,
                                           nullptr, hc, 128, 128, 0, nullptr, rowsum);
  logits_y_loss_k<<<6144, 128, 0, stream>>>(hc, W_clf, b_clf, labels, scal, ecount, outp);

  (void)n_in; (void)out_size; (void)ws_size; (void)in_sizes;
}